// Round 1
// baseline (402.799 us; speedup 1.0000x reference)
//
#include <hip/hip_runtime.h>
#include <math.h>

// PlanarFlow: B=16384 rows, 32 steps, latent 64.
// One wave (64 lanes) per row; lane l owns z[l]. HBM-bound (~287 MB/launch).

constexpr int BATCH = 16384;
constexpr int STEPS = 32;
constexpr int LAT   = 64;
constexpr int IN_W  = STEPS * (2 * LAT + 1) + 2 * LAT;  // 4256

__global__ __launch_bounds__(256)
void planar_flow_kernel(const float* __restrict__ inputs,
                        const float* __restrict__ noise,
                        float* __restrict__ z_out,
                        float* __restrict__ loss_out)
{
    const int lane = threadIdx.x & 63;
    const int wv   = threadIdx.x >> 6;                  // wave within block (0..3)
    const int row  = (blockIdx.x << 2) + wv;            // one row per wave

    const float* rp = inputs + (size_t)row * IN_W;

    // ---- q0 / z0 / KL term ----
    float mu  = rp[lane];                               // [0,64)
    float ls2 = rp[LAT + lane];                         // [64,128)
    float nz  = noise[(size_t)row * LAT + lane];
    // b vector (32 scalars) loaded once, broadcast per-step via shfl
    float bvec = rp[2 * LAT + 2 * STEPS * LAT + (lane & 31)];   // [4224,4256)

    float z = mu + nz * __expf(0.5f * ls2);

    float kl = nz * nz + ls2;
    #pragma unroll
    for (int off = 32; off > 0; off >>= 1)
        kl += __shfl_xor(kl, off, 64);
    float acc = -0.5f * kl;                             // per-row loss accumulator

    const float* up = rp + 2 * LAT;                     // U: [128, 2176)
    const float* wp = rp + 2 * LAT + STEPS * LAT;       // W: [2176, 4224)

    #pragma unroll 4
    for (int s = 0; s < STEPS; ++s) {
        float u = up[s * LAT + lane];
        float w = wp[s * LAT + lane];

        float hv  = w * z;
        float uwv = u * w;
        #pragma unroll
        for (int off = 32; off > 0; off >>= 1) {
            hv  += __shfl_xor(hv,  off, 64);
            uwv += __shfl_xor(uwv, off, 64);
        }
        float h = hv + __shfl(bvec, s, 64);

        // tanh(h) = 1 - 2/(exp(2h)+1); saturates to +/-1 on overflow (correct)
        float e = __expf(2.0f * h);
        float t = 1.0f - 2.0f * __builtin_amdgcn_rcpf(e + 1.0f);

        acc -= __logf(fabsf((1.0f - t * t) * uwv + 1.0f));
        z += u * t;
    }

    // ---- write z (coalesced) ----
    z_out[(size_t)row * LAT + lane] = z;

    // ---- loss: block-reduce then one atomic per block (pre-scaled by 1/B) ----
    __shared__ float partial[4];
    if (lane == 0) partial[wv] = acc;
    __syncthreads();
    if (threadIdx.x == 0) {
        float s = (partial[0] + partial[1] + partial[2] + partial[3]) * (1.0f / BATCH);
        atomicAdd(loss_out, s);
    }
}

extern "C" void kernel_launch(void* const* d_in, const int* in_sizes, int n_in,
                              void* d_out, int out_size, void* d_ws, size_t ws_size,
                              hipStream_t stream)
{
    const float* inputs = (const float*)d_in[0];
    const float* noise  = (const float*)d_in[1];
    float* z_out    = (float*)d_out;
    float* loss_out = (float*)d_out + (size_t)BATCH * LAT;

    // d_out is poisoned 0xAA before every timed launch — zero the loss slot.
    hipMemsetAsync(loss_out, 0, sizeof(float), stream);

    planar_flow_kernel<<<dim3(BATCH / 4), dim3(256), 0, stream>>>(
        inputs, noise, z_out, loss_out);
}

// Round 2
// 384.226 us; speedup vs baseline: 1.0483x; 1.0483x over previous
//
#include <hip/hip_runtime.h>
#include <math.h>

// PlanarFlow: B=16384 rows, 32 steps, latent 64.
// One wave (64 lanes) per row; lane l owns z[l].
// Cross-lane reductions via DPP (VALU pipe) instead of ds_swizzle:
// row_shr 1/2/4/8 + row_bcast15/31 with bound_ctrl=1 -> full sum at lane 63.

constexpr int BATCH = 16384;
constexpr int STEPS = 32;
constexpr int LAT   = 64;
constexpr int IN_W  = STEPS * (2 * LAT + 1) + 2 * LAT;  // 4256

template <int CTRL>
__device__ __forceinline__ float dpp_mov(float x) {
    // bound_ctrl=true: invalid source lanes read 0 (identity for add)
    return __int_as_float(
        __builtin_amdgcn_update_dpp(0, __float_as_int(x), CTRL, 0xF, 0xF, true));
}

// After this, lane 63 holds the sum over all 64 lanes (other lanes: partials).
__device__ __forceinline__ float wave_reduce_to63(float x) {
    x += dpp_mov<0x111>(x);  // row_shr:1
    x += dpp_mov<0x112>(x);  // row_shr:2
    x += dpp_mov<0x114>(x);  // row_shr:4
    x += dpp_mov<0x118>(x);  // row_shr:8
    x += dpp_mov<0x142>(x);  // row_bcast:15
    x += dpp_mov<0x143>(x);  // row_bcast:31
    return x;
}

__device__ __forceinline__ float bcast63(float x) {
    return __int_as_float(__builtin_amdgcn_readlane(__float_as_int(x), 63));
}

__global__ __launch_bounds__(256)
void planar_flow_kernel(const float* __restrict__ inputs,
                        const float* __restrict__ noise,
                        float* __restrict__ z_out,
                        float* __restrict__ loss_out)
{
    const int lane = threadIdx.x & 63;
    const int wv   = threadIdx.x >> 6;                  // wave within block (0..3)
    const int row  = (blockIdx.x << 2) + wv;            // one row per wave

    const float* rp = inputs + (size_t)row * IN_W;

    // ---- q0 / z0 / KL term ----
    float mu  = rp[lane];                               // [0,64)
    float ls2 = rp[LAT + lane];                         // [64,128)
    float nz  = noise[(size_t)row * LAT + lane];
    // b vector (32 scalars) held in lanes 0..31, broadcast per-step via readlane
    float bvec = rp[2 * LAT + 2 * STEPS * LAT + (lane & 31)];   // [4224,4256)

    float z = mu + nz * __expf(0.5f * ls2);

    float kl = wave_reduce_to63(nz * nz + ls2);
    float acc = -0.5f * kl;                    // valid on lane 63 only

    const float* up = rp + 2 * LAT;                     // U: [128, 2176)
    const float* wp = rp + 2 * LAT + STEPS * LAT;       // W: [2176, 4224)

    #pragma unroll 8
    for (int s = 0; s < STEPS; ++s) {
        float u = up[s * LAT + lane];
        float w = wp[s * LAT + lane];

        // h = w.z + b[s]  (full sum at lane 63, broadcast as wave-uniform)
        float hv = wave_reduce_to63(w * z);
        float bs = __int_as_float(__builtin_amdgcn_readlane(__float_as_int(bvec), s));
        float h  = bcast63(hv) + bs;

        // uw = u.w  (only lane 63's value matters; other lanes hold partials)
        float uwv = wave_reduce_to63(u * w);

        // tanh(h) = 1 - 2/(exp(2h)+1); saturates to +/-1 on overflow (correct)
        float e = __expf(2.0f * h);
        float t = 1.0f - 2.0f * __builtin_amdgcn_rcpf(e + 1.0f);

        // loss term: correct on lane 63 (uwv is the full dot there)
        acc -= __logf(fabsf((1.0f - t * t) * uwv + 1.0f));

        z += u * t;
    }

    // ---- write z (coalesced) ----
    z_out[(size_t)row * LAT + lane] = z;

    // ---- loss: block-reduce then one atomic per block (pre-scaled by 1/B) ----
    __shared__ float partial[4];
    if (lane == 63) partial[wv] = acc;
    __syncthreads();
    if (threadIdx.x == 0) {
        float s = (partial[0] + partial[1] + partial[2] + partial[3]) * (1.0f / BATCH);
        atomicAdd(loss_out, s);
    }
}

extern "C" void kernel_launch(void* const* d_in, const int* in_sizes, int n_in,
                              void* d_out, int out_size, void* d_ws, size_t ws_size,
                              hipStream_t stream)
{
    const float* inputs = (const float*)d_in[0];
    const float* noise  = (const float*)d_in[1];
    float* z_out    = (float*)d_out;
    float* loss_out = (float*)d_out + (size_t)BATCH * LAT;

    // d_out is poisoned 0xAA before every timed launch — zero the loss slot.
    hipMemsetAsync(loss_out, 0, sizeof(float), stream);

    planar_flow_kernel<<<dim3(BATCH / 4), dim3(256), 0, stream>>>(
        inputs, noise, z_out, loss_out);
}